// Round 12
// baseline (3704.238 us; speedup 1.0000x reference)
//
#include <hip/hip_runtime.h>
#include <hip/hip_fp16.h>

typedef _Float16 h2f   __attribute__((ext_vector_type(2)));
typedef _Float16 half8 __attribute__((ext_vector_type(8)));
typedef float    f32x4 __attribute__((ext_vector_type(4)));

#define RB 64
#define RT 2048
#define RI 64
#define RH 512
#define C1F 0.9f
#define C2F 0.1f

// W_hidden only (input projection precomputed into WIS): 64 u-groups of
// 8 k-rows = 16 MFMA k-steps of 32.
#define NU      64
#define PIN_KS  12   // k-steps 0..11  -> pinned unified-RF B-frags (192 regs, AGPR-backed)
#define LDS_KS  2    // k-steps 12..13 -> LDS-resident (64 KB)
#define STR_KS  2    // k-steps 14..15 -> streamed 64 KB window (L1+L2, idle vMEM port)

static __device__ __forceinline__ half8 bc8(uint4 v) {
    return __builtin_bit_cast(half8, v);
}

#define MFMA(a, b, c) __builtin_amdgcn_mfma_f32_16x16x32_f16((a), (b), (c), 0, 0, 0)

// Pack W_hidden to f16, plain [u][j]: uint4 entry u*RH+j holds rows 8u..8u+7
// of column j == MFMA B-subfragment: lane l of k-step c, col-tile cb ->
// P[(4c + (l>>4))*RH + cb + (l&15)].
__global__ void prep_pack(const float* __restrict__ W, h2f* __restrict__ P) {
    int e = blockIdx.x * 256 + threadIdx.x;
    if (e >= NU * RH * 4) return;
    int q = e & 3;
    int j = (e >> 2) & (RH - 1);
    int u = e >> 11;
    int k = 8 * u + 2 * q;
    h2f r;
    r.x = (_Float16)W[k * RH + j];
    r.y = (_Float16)W[(k + 1) * RH + j];
    P[e] = r;
}

// WIS[b,t,j] = C2 * sum_i x[b,t,i]*Win[i,j] + sigma[b,t,j], into d_out's
// [B][T][H] region (scan reads each slot before overwriting it).
// WROWS=32 amortizes the win-column register load 4x better than round 11
// (win re-reads were ~2.1 GB of L2 traffic at WROWS=8 -> 0.5 GB).
#define WROWS 32
__global__ __launch_bounds__(512) void wis_gemm(
        const float* __restrict__ x, const float* __restrict__ Win,
        const float* __restrict__ sigma, float* __restrict__ outWIS) {
    const int j = threadIdx.x;
    const long r0 = (long)blockIdx.x * WROWS;

    float win[RI];                                   // Win column j in regs
    #pragma unroll
    for (int i = 0; i < RI; ++i) win[i] = Win[i * RH + j];
    #pragma unroll
    for (int i = 0; i < RI; ++i) asm volatile("" : "+v"(win[i]));  // no re-load

    #pragma unroll 4
    for (int r = 0; r < WROWS; ++r) {
        const float* xr = x + (r0 + r) * RI;         // block-uniform row base
        float a0 = 0.f, a1 = 0.f, a2 = 0.f, a3 = 0.f;
        #pragma unroll
        for (int i = 0; i < RI / 4; ++i) {
            a0 = fmaf(xr[4 * i + 0], win[4 * i + 0], a0);
            a1 = fmaf(xr[4 * i + 1], win[4 * i + 1], a1);
            a2 = fmaf(xr[4 * i + 2], win[4 * i + 2], a2);
            a3 = fmaf(xr[4 * i + 3], win[4 * i + 3], a3);
        }
        long idx = (r0 + r) * RH + j;
        outWIS[idx] = fmaf(C2F, (a0 + a1) + (a2 + a3), sigma[idx]);
    }
}

// One block per batch element; 8 waves; wave w owns cols w*64..w*64+63;
// lane l finalizes col w*64+l (A-broadcast MFMA, layout verified rounds 7-11).
// W tiers: 192 unified-RF regs + 64 KB LDS + 64 KB step-invariant stream.
__global__
__attribute__((amdgpu_flat_work_group_size(512, 512), amdgpu_waves_per_eu(2, 2)))
void rnn_scan(
        const float* __restrict__ h0,     // [RB][RH] f32
        const uint4* __restrict__ P,      // packed f16 W_hidden
        float* __restrict__ out)          // [RB][RT][RH] holds WIS on entry;
                                          // overwritten with h; then h_f tail
{
    const int b    = blockIdx.x;
    const int tid  = threadIdx.x;
    const int wave = tid >> 6;
    const int lane = tid & 63;
    const int g    = lane >> 4;          // B k-subrow group
    const int li   = lane & 15;          // B/C column within tile
    const int wb   = wave * 64;
    const int col  = wb + lane;

    __shared__ __align__(16) uint4    Wl[LDS_KS * 4 * RH];  // 65536 B
    __shared__ __align__(16) _Float16 th[2][RH];            // 2048 B

    // LDS tier: k-steps 12..13
    for (int e = tid; e < LDS_KS * 4 * RH; e += RH)
        Wl[e] = P[PIN_KS * 4 * RH + e];

    // pinned B-frags: k-steps 0..11 (asm pin -> non-rematerializable; backed
    // by the AGPR half of the unified RF, read directly by MFMA)
    uint4 bp[PIN_KS][4];
    #pragma unroll
    for (int c = 0; c < PIN_KS; ++c)
        #pragma unroll
        for (int n = 0; n < 4; ++n)
            bp[c][n] = P[(4 * c + g) * RH + wb + n * 16 + li];
    #pragma unroll
    for (int c = 0; c < PIN_KS; ++c)
        #pragma unroll
        for (int n = 0; n < 4; ++n)
            asm volatile("" : "+v"(bp[c][n].x), "+v"(bp[c][n].y),
                               "+v"(bp[c][n].z), "+v"(bp[c][n].w));

    float* orow = out + (size_t)b * RT * RH;

    float h = h0[b * RH + col];
    {
        float e2 = __expf(2.0f * h);
        th[0][col] = (_Float16)(1.0f - 2.0f / (e2 + 1.0f));
    }
    __syncthreads();

    for (int t = 0; t < RT; ++t) {
        const uint4* thq = (const uint4*)th[t & 1];
        _Float16*    thw = th[(t & 1) ^ 1];

        // own slot: WIS = c2*(x@Win)+sigma, precomputed; read before write.
        float wis = orow[(size_t)t * RH + col];

        // streamed k-steps 14..15: step-invariant 64 KB window on the
        // otherwise-idle vMEM port. c=0 issued here; c=1 issued after the
        // pinned phase (staggered -> only 16 extra VGPRs live at a time).
        int off0 = 0;
        asm volatile("" : "+v"(off0));
        const uint4* Pst =
            P + (size_t)((PIN_KS + LDS_KS) * 4 + g) * RH + wb + li + off0;
        uint4 s00 = Pst[0], s01 = Pst[16], s02 = Pst[32], s03 = Pst[48];

        f32x4 acc0 = {0.f, 0.f, 0.f, 0.f};
        f32x4 acc1 = {0.f, 0.f, 0.f, 0.f};
        f32x4 acc2 = {0.f, 0.f, 0.f, 0.f};
        f32x4 acc3 = {0.f, 0.f, 0.f, 0.f};

        // ---- pinned k-steps 0..11 (B operands read straight from AGPRs)
        #pragma unroll
        for (int c = 0; c < PIN_KS; ++c) {
            half8 a = bc8(thq[4 * c + g]);     // A = th broadcast to all rows
            acc0 = MFMA(a, bc8(bp[c][0]), acc0);
            acc1 = MFMA(a, bc8(bp[c][1]), acc1);
            acc2 = MFMA(a, bc8(bp[c][2]), acc2);
            acc3 = MFMA(a, bc8(bp[c][3]), acc3);
        }

        // issue second streamed k-step; consumed ~12 MFMAs later
        const uint4* Pst2 = Pst + 4 * RH;
        uint4 s10 = Pst2[0], s11 = Pst2[16], s12 = Pst2[32], s13 = Pst2[48];

        // ---- LDS k-steps 12..13
        #pragma unroll
        for (int c = 0; c < LDS_KS; ++c) {
            half8 a = bc8(thq[4 * (PIN_KS + c) + g]);
            const uint4* wl = &Wl[(4 * c + g) * RH + wb + li];
            uint4 w0 = wl[0], w1 = wl[16], w2 = wl[32], w3 = wl[48];
            acc0 = MFMA(a, bc8(w0), acc0);
            acc1 = MFMA(a, bc8(w1), acc1);
            acc2 = MFMA(a, bc8(w2), acc2);
            acc3 = MFMA(a, bc8(w3), acc3);
        }
        // ---- streamed k-step 14
        {
            half8 a = bc8(thq[4 * (PIN_KS + LDS_KS) + g]);
            acc0 = MFMA(a, bc8(s00), acc0);
            acc1 = MFMA(a, bc8(s01), acc1);
            acc2 = MFMA(a, bc8(s02), acc2);
            acc3 = MFMA(a, bc8(s03), acc3);
        }
        // ---- streamed k-step 15
        {
            half8 a = bc8(thq[4 * (PIN_KS + LDS_KS + 1) + g]);
            acc0 = MFMA(a, bc8(s10), acc0);
            acc1 = MFMA(a, bc8(s11), acc1);
            acc2 = MFMA(a, bc8(s12), acc2);
            acc3 = MFMA(a, bc8(s13), acc3);
        }

        // lane l's column lives in tile g; rows identical -> element .x
        float a = (g < 2) ? ((g == 0) ? acc0.x : acc1.x)
                          : ((g == 2) ? acc2.x : acc3.x);

        float hn = fmaf(C1F, h, fmaf(C2F, a, wis));
        orow[(size_t)t * RH + col] = hn;
        h = hn;

        float e2 = __expf(2.0f * hn);
        thw[col] = (_Float16)(1.0f - 2.0f / (e2 + 1.0f));
        __syncthreads();
    }

    out[(size_t)RB * RT * RH + (size_t)b * RH + col] = h;
}

extern "C" void kernel_launch(void* const* d_in, const int* in_sizes, int n_in,
                              void* d_out, int out_size, void* d_ws, size_t ws_size,
                              hipStream_t stream) {
    const float* x   = (const float*)d_in[0];
    const float* Win = (const float*)d_in[1];
    const float* Wh  = (const float*)d_in[2];
    const float* sg  = (const float*)d_in[3];
    const float* h0  = (const float*)d_in[4];
    float* out = (float*)d_out;

    h2f* P = (h2f*)d_ws;   // 512 KB packed W_hidden

    const int n_entries = NU * RH * 4;
    hipLaunchKernelGGL(prep_pack, dim3((n_entries + 255) / 256), dim3(256), 0, stream,
                       Wh, P);
    hipLaunchKernelGGL(wis_gemm, dim3(RB * RT / WROWS), dim3(RH), 0, stream,
                       x, Win, sg, out);
    hipLaunchKernelGGL(rnn_scan, dim3(RB), dim3(RH), 0, stream,
                       h0, (const uint4*)d_ws, out);
}

// Round 13
// 3157.981 us; speedup vs baseline: 1.1730x; 1.1730x over previous
//
#include <hip/hip_runtime.h>
#include <hip/hip_fp16.h>

typedef _Float16 h2f   __attribute__((ext_vector_type(2)));
typedef _Float16 half8 __attribute__((ext_vector_type(8)));
typedef float    f32x4 __attribute__((ext_vector_type(4)));

#define RB 64
#define RT 2048
#define RI 64
#define RH 512
#define C1F 0.9f
#define C2F 0.1f

// W_hidden only (input projection precomputed into WIS): 64 u-groups of
// 8 k-rows = 16 MFMA k-steps of 32.
#define NU      64
#define PIN_KS  12   // k-steps 0..11  -> pinned unified-RF B-frags (192 regs, AGPR-backed)
#define LDS_KS  3    // k-steps 12..14 -> LDS-resident (96 KB)
#define STR_KS  1    // k-step  15     -> streamed, 32 KB step-invariant window
                     //                   (fits vL1D exactly; idle vMEM port)

static __device__ __forceinline__ half8 bc8(uint4 v) {
    return __builtin_bit_cast(half8, v);
}

#define MFMA(a, b, c) __builtin_amdgcn_mfma_f32_16x16x32_f16((a), (b), (c), 0, 0, 0)

// Pack W_hidden to f16, plain [u][j]: uint4 entry u*RH+j holds rows 8u..8u+7
// of column j == MFMA B-subfragment: lane l of k-step c, col-tile cb ->
// P[(4c + (l>>4))*RH + cb + (l&15)].
__global__ void prep_pack(const float* __restrict__ W, h2f* __restrict__ P) {
    int e = blockIdx.x * 256 + threadIdx.x;
    if (e >= NU * RH * 4) return;
    int q = e & 3;
    int j = (e >> 2) & (RH - 1);
    int u = e >> 11;
    int k = 8 * u + 2 * q;
    h2f r;
    r.x = (_Float16)W[k * RH + j];
    r.y = (_Float16)W[(k + 1) * RH + j];
    P[e] = r;
}

// WIS[b,t,j] = C2 * sum_i x[b,t,i]*Win[i,j] + sigma[b,t,j], into d_out's
// [B][T][H] region (scan reads each slot before overwriting it).
// WROWS=8 + direct wave-uniform x reads: measured-best config (round 11).
#define WROWS 8
__global__ __launch_bounds__(512) void wis_gemm(
        const float* __restrict__ x, const float* __restrict__ Win,
        const float* __restrict__ sigma, float* __restrict__ outWIS) {
    const int j = threadIdx.x;
    const long r0 = (long)blockIdx.x * WROWS;

    float win[RI];                                   // Win column j in regs
    #pragma unroll
    for (int i = 0; i < RI; ++i) win[i] = Win[i * RH + j];
    #pragma unroll
    for (int i = 0; i < RI; ++i) asm volatile("" : "+v"(win[i]));  // no re-load

    #pragma unroll
    for (int r = 0; r < WROWS; ++r) {
        const float* xr = x + (r0 + r) * RI;         // wave-uniform row base
        float a0 = 0.f, a1 = 0.f, a2 = 0.f, a3 = 0.f;
        #pragma unroll
        for (int i = 0; i < RI / 4; ++i) {
            a0 = fmaf(xr[4 * i + 0], win[4 * i + 0], a0);
            a1 = fmaf(xr[4 * i + 1], win[4 * i + 1], a1);
            a2 = fmaf(xr[4 * i + 2], win[4 * i + 2], a2);
            a3 = fmaf(xr[4 * i + 3], win[4 * i + 3], a3);
        }
        long idx = (r0 + r) * RH + j;
        outWIS[idx] = fmaf(C2F, (a0 + a1) + (a2 + a3), sigma[idx]);
    }
}

// One block per batch element; 8 waves; wave w owns cols w*64..w*64+63;
// lane l finalizes col w*64+l (A-broadcast MFMA, layout verified rounds 7-12).
// W tiers: 192 unified-RF regs + 96 KB LDS + 32 KB L1-resident stream.
// Loop barrier is raw s_barrier + lgkmcnt(0) only: __syncthreads would also
// drain vmcnt (out-store ack + stream loads) every step, which nothing after
// the barrier depends on -- each thread's WIS slot is read-before-write by
// the SAME thread, and stream loads are consumed pre-barrier by data dep.
__global__
__attribute__((amdgpu_flat_work_group_size(512, 512), amdgpu_waves_per_eu(2, 2)))
void rnn_scan(
        const float* __restrict__ h0,     // [RB][RH] f32
        const uint4* __restrict__ P,      // packed f16 W_hidden
        float* __restrict__ out)          // [RB][RT][RH] holds WIS on entry;
                                          // overwritten with h; then h_f tail
{
    const int b    = blockIdx.x;
    const int tid  = threadIdx.x;
    const int wave = tid >> 6;
    const int lane = tid & 63;
    const int g    = lane >> 4;          // B k-subrow group
    const int li   = lane & 15;          // B/C column within tile
    const int wb   = wave * 64;
    const int col  = wb + lane;

    __shared__ __align__(16) uint4    Wl[LDS_KS * 4 * RH];  // 98304 B
    __shared__ __align__(16) _Float16 th[2][RH];            // 2048 B

    // LDS tier: k-steps 12..14
    for (int e = tid; e < LDS_KS * 4 * RH; e += RH)
        Wl[e] = P[PIN_KS * 4 * RH + e];

    // pinned B-frags: k-steps 0..11 (asm pin -> non-rematerializable; backed
    // by the AGPR half of the unified RF, read directly by MFMA)
    uint4 bp[PIN_KS][4];
    #pragma unroll
    for (int c = 0; c < PIN_KS; ++c)
        #pragma unroll
        for (int n = 0; n < 4; ++n)
            bp[c][n] = P[(4 * c + g) * RH + wb + n * 16 + li];
    #pragma unroll
    for (int c = 0; c < PIN_KS; ++c)
        #pragma unroll
        for (int n = 0; n < 4; ++n)
            asm volatile("" : "+v"(bp[c][n].x), "+v"(bp[c][n].y),
                               "+v"(bp[c][n].z), "+v"(bp[c][n].w));

    float* orow = out + (size_t)b * RT * RH;

    float h = h0[b * RH + col];
    {
        float e2 = __expf(2.0f * h);
        th[0][col] = (_Float16)(1.0f - 2.0f / (e2 + 1.0f));
    }
    __syncthreads();

    for (int t = 0; t < RT; ++t) {
        const uint4* thq = (const uint4*)th[t & 1];
        _Float16*    thw = th[(t & 1) ^ 1];

        // own slot: WIS = c2*(x@Win)+sigma, precomputed; read before write.
        float wis = orow[(size_t)t * RH + col];

        // streamed k-step 15: step-invariant 32 KB window -> L1 hits after
        // step 0. Opaque 0 keeps the loads inside the t-loop (would otherwise
        // hoist into 16 more pinned regs and risk the round-3 spill).
        int off0 = 0;
        asm volatile("" : "+v"(off0));
        const uint4* Pst =
            P + (size_t)((PIN_KS + LDS_KS) * 4 + g) * RH + wb + li + off0;
        uint4 sf0 = Pst[0], sf1 = Pst[16], sf2 = Pst[32], sf3 = Pst[48];

        f32x4 acc0 = {0.f, 0.f, 0.f, 0.f};
        f32x4 acc1 = {0.f, 0.f, 0.f, 0.f};
        f32x4 acc2 = {0.f, 0.f, 0.f, 0.f};
        f32x4 acc3 = {0.f, 0.f, 0.f, 0.f};

        // ---- pinned k-steps 0..11 (B operands read straight from AGPRs)
        #pragma unroll
        for (int c = 0; c < PIN_KS; ++c) {
            half8 a = bc8(thq[4 * c + g]);     // A = th broadcast to all rows
            acc0 = MFMA(a, bc8(bp[c][0]), acc0);
            acc1 = MFMA(a, bc8(bp[c][1]), acc1);
            acc2 = MFMA(a, bc8(bp[c][2]), acc2);
            acc3 = MFMA(a, bc8(bp[c][3]), acc3);
        }
        // ---- LDS k-steps 12..14
        #pragma unroll
        for (int c = 0; c < LDS_KS; ++c) {
            half8 a = bc8(thq[4 * (PIN_KS + c) + g]);
            const uint4* wl = &Wl[(4 * c + g) * RH + wb + li];
            uint4 w0 = wl[0], w1 = wl[16], w2 = wl[32], w3 = wl[48];
            acc0 = MFMA(a, bc8(w0), acc0);
            acc1 = MFMA(a, bc8(w1), acc1);
            acc2 = MFMA(a, bc8(w2), acc2);
            acc3 = MFMA(a, bc8(w3), acc3);
        }
        // ---- streamed k-step 15 (loads issued at loop top, consumed last)
        {
            half8 a = bc8(thq[4 * (PIN_KS + LDS_KS) + g]);
            acc0 = MFMA(a, bc8(sf0), acc0);
            acc1 = MFMA(a, bc8(sf1), acc1);
            acc2 = MFMA(a, bc8(sf2), acc2);
            acc3 = MFMA(a, bc8(sf3), acc3);
        }

        // lane l's column lives in tile g; rows identical -> element .x
        float a = (g < 2) ? ((g == 0) ? acc0.x : acc1.x)
                          : ((g == 2) ? acc2.x : acc3.x);

        float hn = fmaf(C1F, h, fmaf(C2F, a, wis));

        // publish th FIRST (it gates the barrier), then fire the store
        float e2 = __expf(2.0f * hn);
        thw[col] = (_Float16)(1.0f - 2.0f / (e2 + 1.0f));
        orow[(size_t)t * RH + col] = hn;
        h = hn;

        // raw barrier: wait only for LDS ops (th publish), not vmcnt drain
        asm volatile("s_waitcnt lgkmcnt(0)\n\ts_barrier" ::: "memory");
    }

    out[(size_t)RB * RT * RH + (size_t)b * RH + col] = h;
}

extern "C" void kernel_launch(void* const* d_in, const int* in_sizes, int n_in,
                              void* d_out, int out_size, void* d_ws, size_t ws_size,
                              hipStream_t stream) {
    const float* x   = (const float*)d_in[0];
    const float* Win = (const float*)d_in[1];
    const float* Wh  = (const float*)d_in[2];
    const float* sg  = (const float*)d_in[3];
    const float* h0  = (const float*)d_in[4];
    float* out = (float*)d_out;

    h2f* P = (h2f*)d_ws;   // 512 KB packed W_hidden

    const int n_entries = NU * RH * 4;
    hipLaunchKernelGGL(prep_pack, dim3((n_entries + 255) / 256), dim3(256), 0, stream,
                       Wh, P);
    hipLaunchKernelGGL(wis_gemm, dim3(RB * RT / WROWS), dim3(RH), 0, stream,
                       x, Win, sg, out);
    hipLaunchKernelGGL(rnn_scan, dim3(RB), dim3(RH), 0, stream,
                       h0, (const uint4*)d_ws, out);
}